// Round 1
// baseline (341.416 us; speedup 1.0000x reference)
//
#include <hip/hip_runtime.h>
#include <cstdint>

// Instant-NGP hash-grid embedder, 2-phase with level->XCD affinity.
//
// Phase A (EXACT R2 form — 226us measured): one block = one level x 256
//   points, 1 pt/thread. blockIdx%8 pins level pairs (i, 15-i) to one XCD
//   residue (verified R2: FETCH 1.56GB -> 149MB). Phase A sits at ~97% of
//   the per-XCD L2 request-throughput roofline (8.4M random 8B gathers/XCD
//   / 16 ch / 2.4GHz = 218us) — R5 showed more per-thread MLP does NOT help.
// Phase B: LDS tile transpose ws[c][l][p] -> out[b][f*16+l].
//   R6 THEORY: old level-major ws ([l][B], 4MB level stride) made phase B's
//   16 loads/thread a 4MB-stride power-of-two sweep -> DRAM-bank/L3-slice
//   aliasing; store-coalescing fix (R5->R6) was NEUTRAL (334->336us), so
//   reads, not stores, are the phase-B limiter (128MB should be ~20-30us,
//   measured ~110us = 1.1TB/s). This round: chunk-major ws layout
//   [chunk][level][point] -> each phase-B block reads one CONTIGUOUS 32KB
//   extent (same instr mix: 16x dwordx2 loads, 32x b32 LDS writes, 2-way
//   free banks). Phase A store stays one coalesced 2KB run per block.
//
// R4 LESSON: no __builtin_nontemporal_* anywhere (regressed both phases).
// R5 LESSON: phase A is L2-request-bound, not latency-bound.
//
// Discrete steps (bottom_left trunc) replicated in float64 to match the
// NumPy reference under NEP-50 promotion. Resolutions hardcoded to the
// exact-math floor(16 * 2^(l/3)) values.

constexpr int NLEV = 16;
constexpr uint32_t HM_MASK = (1u << 19) - 1;

__device__ __constant__ double c_res[NLEV] = {
    16.0, 20.0, 25.0, 32.0, 40.0, 50.0, 64.0, 80.0,
    101.0, 128.0, 161.0, 203.0, 256.0, 322.0, 406.0, 512.0
};

__device__ __forceinline__ void ngp_eval_point(
    int b, int lev,
    const float* __restrict__ x,
    const float2* __restrict__ tab2,
    float bm0, float bm1, float bm2,
    float d0, float d1, float d2,
    float& f0, float& f1)
{
    const float fx0 = x[3 * b + 0];
    const float fx1 = x[3 * b + 1];
    const float fx2 = x[3 * b + 2];

    const double res = c_res[lev];
    const double g0 = (double)d0 / res;
    const double g1 = (double)d1 / res;
    const double g2 = (double)d2 / res;
    const double q0 = (double)(fx0 - bm0) / g0;
    const double q1 = (double)(fx1 - bm1) / g1;
    const double q2 = (double)(fx2 - bm2) / g2;
    const int i0 = (int)q0;
    const int i1 = (int)q1;
    const int i2 = (int)q2;
    const float w0 = (float)(q0 - (double)i0);
    const float w1 = (float)(q1 - (double)i1);
    const float w2 = (float)(q2 - (double)i2);

    const uint32_t P1 = 2654435761u, P2 = 805459861u;
    const uint32_t h0a = (uint32_t)i0;
    const uint32_t h0b = h0a + 1u;
    const uint32_t h1a = (uint32_t)i1 * P1;
    const uint32_t h1b = h1a + P1;
    const uint32_t h2a = (uint32_t)i2 * P2;
    const uint32_t h2b = h2a + P2;
    const uint32_t base = (uint32_t)lev << 19;

    const float2 v000 = tab2[base + ((h0a ^ h1a ^ h2a) & HM_MASK)];
    const float2 v001 = tab2[base + ((h0a ^ h1a ^ h2b) & HM_MASK)];
    const float2 v010 = tab2[base + ((h0a ^ h1b ^ h2a) & HM_MASK)];
    const float2 v011 = tab2[base + ((h0a ^ h1b ^ h2b) & HM_MASK)];
    const float2 v100 = tab2[base + ((h0b ^ h1a ^ h2a) & HM_MASK)];
    const float2 v101 = tab2[base + ((h0b ^ h1a ^ h2b) & HM_MASK)];
    const float2 v110 = tab2[base + ((h0b ^ h1b ^ h2a) & HM_MASK)];
    const float2 v111 = tab2[base + ((h0b ^ h1b ^ h2b) & HM_MASK)];

    const float u0 = 1.0f - w0, u1 = 1.0f - w1, u2 = 1.0f - w2;
    const float waa = u1 * u2;
    const float wab = u1 * w2;
    const float wba = w1 * u2;
    const float wbb = w1 * w2;

    f0 = u0 * (waa * v000.x + wab * v001.x + wba * v010.x + wbb * v011.x)
       + w0 * (waa * v100.x + wab * v101.x + wba * v110.x + wbb * v111.x);
    f1 = u0 * (waa * v000.y + wab * v001.y + wba * v010.y + wbb * v011.y)
       + w0 * (waa * v100.y + wab * v101.y + wba * v110.y + wbb * v111.y);
}

// ---------------- Phase A: per-level gather+interp, chunk-major ws ----------
// EXACT R2 gather structure (measured 226us); only the ws store layout
// changed: ws2[chunk*4096 + lev*256 + t] (chunk-major, 32KB per chunk).
// Still one coalesced 2KB float2 run per block (512B per wave-instr).
__global__ __launch_bounds__(256)
void ngp_levels_kernel(const float* __restrict__ x,
                       const float* __restrict__ table,
                       const float* __restrict__ box_min,
                       const float* __restrict__ box_max,
                       float2* __restrict__ ws,
                       int B, int chunks)
{
    // XCD-affinity: residue = blockIdx%8 -> XCD (HW round-robin dispatch).
    // XCD residue i: level i (phase 1, coarse) then 15-i (phase 2, fine).
    const int xcd = blockIdx.x & 7;
    const int s   = blockIdx.x >> 3;
    const int lev   = (s < chunks) ? xcd : (15 - xcd);
    const int chunk = (s < chunks) ? s : (s - chunks);
    const int b = chunk * 256 + threadIdx.x;
    if (b >= B) return;

    const float bm0 = box_min[0], bm1 = box_min[1], bm2 = box_min[2];
    const float d0 = box_max[0] - bm0;
    const float d1 = box_max[1] - bm1;
    const float d2 = box_max[2] - bm2;

    float f0, f1;
    ngp_eval_point(b, lev, x, (const float2*)table,
                   bm0, bm1, bm2, d0, d1, d2, f0, f1);

    // chunk-major: [chunk][level][point], float2 units. 8B coalesced.
    ws[(size_t)chunk * (NLEV * 256) + lev * 256 + threadIdx.x]
        = make_float2(f0, f1);
}

// ---------------- Phase B: LDS tile transpose ws[c][l][p] -> out[b][f*16+l] -
// Block = 256 points = one 32KB CONTIGUOUS ws chunk. Requires B % 256 == 0.
// LDS layout: float rows indexed r = 2*l + f, row stride 257 floats (pad
// breaks the 32-point bank alias in stage 2). Size = 32*257*4 = 32896 B.
constexpr int LDS_STRIDE = 257;

__global__ __launch_bounds__(256)
void ngp_transpose_kernel(const float2* __restrict__ ws,
                          float* __restrict__ out,
                          int B)
{
    __shared__ float lds[32 * LDS_STRIDE];

    const int t  = threadIdx.x;
    const int c  = blockIdx.x;           // chunk id
    const int P0 = c * 256;

    // Stage 1: 16 coalesced loads/thread spanning ONE contiguous 32KB
    // extent (512B per wave-instr, sequential). -> LDS rows r = 2l+f.
    // Bank: ((2l*257 + t)) % 32 = (2l + t) % 32 -> 2 lanes/bank (free).
    const float2* __restrict__ wsc = ws + (size_t)c * (NLEV * 256);
#pragma unroll
    for (int l = 0; l < NLEV; ++l) {
        const float2 v = wsc[l * 256 + t];
        lds[(2 * l)     * LDS_STRIDE + t] = v.x;
        lds[(2 * l + 1) * LDS_STRIDE + t] = v.y;
    }
    __syncthreads();

    // Stage 2: each store instr writes 1KB fully contiguous.
    // Lane t, iter j covers out flat range [P0*32 + j*1024 + 4t, +4):
    //   point p = j*32 + (t>>3), f = (t>>2)&1, l = (t&3)*4 + k.
    const int p_lo = t >> 3;
    const int f    = (t >> 2) & 1;
    const int l0   = (t & 3) * 4;
#pragma unroll
    for (int j = 0; j < 8; ++j) {
        const int p = j * 32 + p_lo;
        float4 v;
        v.x = lds[(2 * (l0 + 0) + f) * LDS_STRIDE + p];
        v.y = lds[(2 * (l0 + 1) + f) * LDS_STRIDE + p];
        v.z = lds[(2 * (l0 + 2) + f) * LDS_STRIDE + p];
        v.w = lds[(2 * (l0 + 3) + f) * LDS_STRIDE + p];
        *(float4*)(out + (size_t)P0 * 32 + j * 1024 + t * 4) = v;
    }
}

// ---------------- Fallback: fused kernel (if ws too small / B%256!=0) -------
__global__ __launch_bounds__(256)
void ngp_embed_fused_kernel(const float* __restrict__ x,
                            const float* __restrict__ table,
                            const float* __restrict__ box_min,
                            const float* __restrict__ box_max,
                            float* __restrict__ out,
                            int B)
{
    const int gid = blockIdx.x * 256 + threadIdx.x;
    const int b = gid >> 4;
    const int l = gid & 15;
    if (b >= B) return;

    const float bm0 = box_min[0], bm1 = box_min[1], bm2 = box_min[2];
    const float d0 = box_max[0] - bm0;
    const float d1 = box_max[1] - bm1;
    const float d2 = box_max[2] - bm2;

    float f0, f1;
    ngp_eval_point(b, l, x, (const float2*)table,
                   bm0, bm1, bm2, d0, d1, d2, f0, f1);

    out[b * 32 + l]      = f0;
    out[b * 32 + 16 + l] = f1;
}

extern "C" void kernel_launch(void* const* d_in, const int* in_sizes, int n_in,
                              void* d_out, int out_size, void* d_ws, size_t ws_size,
                              hipStream_t stream) {
    const float* x       = (const float*)d_in[0];
    const float* table   = (const float*)d_in[1];
    const float* box_min = (const float*)d_in[2];
    const float* box_max = (const float*)d_in[3];
    float* out = (float*)d_out;

    const int B = in_sizes[0] / 3;
    const size_t ws_needed = (size_t)B * NLEV * sizeof(float2);

    if (ws_size >= ws_needed && (B % 256) == 0) {
        const int chunks = B / 256;               // per level, 256 pts/block
        const int gridA = 8 * 2 * chunks;         // 8 residues x 2 levels
        hipLaunchKernelGGL(ngp_levels_kernel, dim3(gridA), dim3(256), 0, stream,
                           x, table, box_min, box_max, (float2*)d_ws, B, chunks);
        const int gridB = B / 256;
        hipLaunchKernelGGL(ngp_transpose_kernel, dim3(gridB), dim3(256), 0, stream,
                           (const float2*)d_ws, out, B);
    } else {
        const int total = B * NLEV;
        const int blocks = (total + 255) / 256;
        hipLaunchKernelGGL(ngp_embed_fused_kernel, dim3(blocks), dim3(256), 0, stream,
                           x, table, box_min, box_max, out, B);
    }
}